// Round 2
// baseline (1640.376 us; speedup 1.0000x reference)
//
#include <hip/hip_runtime.h>
#include <hip/hip_bf16.h>
#include <math.h>

// N=10000, E=160000, C=16, C0=32, L=2, M=5, H=8, R_IN=32, R_HID=128, REQ=384

__device__ __forceinline__ float waveSum(float v) {
#pragma unroll
  for (int m = 1; m < 64; m <<= 1) v += __shfl_xor(v, m, 64);
  return v;
}
__device__ __forceinline__ unsigned encf(float f) {
  unsigned u = __float_as_uint(f);
  return (u & 0x80000000u) ? ~u : (u | 0x80000000u);
}
__device__ __forceinline__ float decf(unsigned u) {
  return (u & 0x80000000u) ? __uint_as_float(u & 0x7FFFFFFFu) : __uint_as_float(~u);
}

// 32x128 partial GEMM over one k-chunk of 32 (acc += A[32 rows][k0..k0+32) * W^T)
__device__ __forceinline__ void gemm32(const float* A, int lda, int koff,
                                       const float* W, int eg, int jg,
                                       float acc[4][4]) {
  for (int k = 0; k < 32; k += 4) {
    float4 fa[4], fw[4];
#pragma unroll
    for (int r = 0; r < 4; r++) fa[r] = *(const float4*)(A + (4 * eg + r) * lda + koff + k);
#pragma unroll
    for (int q = 0; q < 4; q++) fw[q] = *(const float4*)(W + (4 * jg + q) * 36 + k);
#pragma unroll
    for (int r = 0; r < 4; r++)
#pragma unroll
      for (int q = 0; q < 4; q++)
        acc[r][q] += fa[r].x * fw[q].x + fa[r].y * fw[q].y +
                     fa[r].z * fw[q].z + fa[r].w * fw[q].w;
  }
}

// ---------------------------------------------------------------------------
// Kernel 1: fused radial MLP for a chunk of edges: (CE,32)->LN+silu(128)
//           ->LN+silu(128)->384.  32 edges / 256-thread block.
// ---------------------------------------------------------------------------
__global__ __launch_bounds__(256) void radial_kernel(
    const float* __restrict__ ef,
    const float* __restrict__ W1, const float* __restrict__ b1,
    const float* __restrict__ g1, const float* __restrict__ be1,
    const float* __restrict__ W2, const float* __restrict__ b2,
    const float* __restrict__ g2, const float* __restrict__ be2,
    const float* __restrict__ W3, const float* __restrict__ b3,
    float* __restrict__ w_chunk, int e0) {
  __shared__ float sA[32][36];
  __shared__ float sW[128][36];
  __shared__ float sH1[32][132];
  __shared__ float sH2[32][132];
  __shared__ float sMu[32], sRs[32];
  const int tid = threadIdx.x;
  const int le0 = blockIdx.x * 32;
  const int jg = tid >> 3, eg = tid & 7;

  for (int idx = tid; idx < 32 * 32; idx += 256) {
    int e = idx >> 5, k = idx & 31;
    sA[e][k] = ef[(size_t)(e0 + le0 + e) * 32 + k];
  }
  for (int idx = tid; idx < 32 * 128; idx += 256) {
    int k = idx >> 7, u = idx & 127;
    sW[u][k] = W1[idx];
  }
  __syncthreads();
  // ---- layer 1 ----
  {
    float acc[4][4] = {};
    gemm32(&sA[0][0], 36, 0, &sW[0][0], eg, jg, acc);
    float4 bb = *(const float4*)&b1[4 * jg];
#pragma unroll
    for (int r = 0; r < 4; r++)
      *(float4*)&sH1[4 * eg + r][4 * jg] =
          make_float4(acc[r][0] + bb.x, acc[r][1] + bb.y, acc[r][2] + bb.z, acc[r][3] + bb.w);
  }
  __syncthreads();
  // LN + silu on sH1
  {
    int e = tid >> 3, r8 = tid & 7;
    float s1 = 0.f, s2 = 0.f;
    for (int j = r8 * 16; j < r8 * 16 + 16; j++) { float v = sH1[e][j]; s1 += v; s2 += v * v; }
    s1 += __shfl_xor(s1, 1, 64); s2 += __shfl_xor(s2, 1, 64);
    s1 += __shfl_xor(s1, 2, 64); s2 += __shfl_xor(s2, 2, 64);
    s1 += __shfl_xor(s1, 4, 64); s2 += __shfl_xor(s2, 4, 64);
    if (r8 == 0) { float mu = s1 / 128.f, var = s2 / 128.f - mu * mu; sMu[e] = mu; sRs[e] = rsqrtf(var + 1e-5f); }
  }
  __syncthreads();
  for (int idx = tid; idx < 32 * 128; idx += 256) {
    int e = idx >> 7, j = idx & 127;
    float v = (sH1[e][j] - sMu[e]) * sRs[e] * g1[j] + be1[j];
    sH1[e][j] = v / (1.f + __expf(-v));
  }
  // ---- layer 2 ----
  {
    float acc[4][4] = {};
    for (int kc = 0; kc < 4; kc++) {
      __syncthreads();
      for (int idx = tid; idx < 32 * 128; idx += 256) {
        int kk = idx >> 7, u = idx & 127;
        sW[u][kk] = W2[(size_t)(kc * 32 + kk) * 128 + u];
      }
      __syncthreads();
      gemm32(&sH1[0][0], 132, kc * 32, &sW[0][0], eg, jg, acc);
    }
    float4 bb = *(const float4*)&b2[4 * jg];
#pragma unroll
    for (int r = 0; r < 4; r++)
      *(float4*)&sH2[4 * eg + r][4 * jg] =
          make_float4(acc[r][0] + bb.x, acc[r][1] + bb.y, acc[r][2] + bb.z, acc[r][3] + bb.w);
  }
  __syncthreads();
  {
    int e = tid >> 3, r8 = tid & 7;
    float s1 = 0.f, s2 = 0.f;
    for (int j = r8 * 16; j < r8 * 16 + 16; j++) { float v = sH2[e][j]; s1 += v; s2 += v * v; }
    s1 += __shfl_xor(s1, 1, 64); s2 += __shfl_xor(s2, 1, 64);
    s1 += __shfl_xor(s1, 2, 64); s2 += __shfl_xor(s2, 2, 64);
    s1 += __shfl_xor(s1, 4, 64); s2 += __shfl_xor(s2, 4, 64);
    if (r8 == 0) { float mu = s1 / 128.f, var = s2 / 128.f - mu * mu; sMu[e] = mu; sRs[e] = rsqrtf(var + 1e-5f); }
  }
  __syncthreads();
  for (int idx = tid; idx < 32 * 128; idx += 256) {
    int e = idx >> 7, j = idx & 127;
    float v = (sH2[e][j] - sMu[e]) * sRs[e] * g2[j] + be2[j];
    sH2[e][j] = v / (1.f + __expf(-v));
  }
  // ---- layer 3 (384 cols in 3 chunks of 128) ----
  for (int cc = 0; cc < 3; cc++) {
    float acc[4][4] = {};
    for (int kc = 0; kc < 4; kc++) {
      __syncthreads();
      for (int idx = tid; idx < 32 * 128; idx += 256) {
        int kk = idx >> 7, u = idx & 127;
        sW[u][kk] = W3[(size_t)(kc * 32 + kk) * 384 + cc * 128 + u];
      }
      __syncthreads();
      gemm32(&sH2[0][0], 132, kc * 32, &sW[0][0], eg, jg, acc);
    }
    int col = cc * 128 + 4 * jg;
    float4 bb = *(const float4*)&b3[col];
#pragma unroll
    for (int r = 0; r < 4; r++)
      *(float4*)&w_chunk[(size_t)(le0 + 4 * eg + r) * 384 + col] =
          make_float4(acc[r][0] + bb.x, acc[r][1] + bb.y, acc[r][2] + bb.z, acc[r][3] + bb.w);
  }
}

// ---------------------------------------------------------------------------
// Kernel 2: per-edge q/k(/v) + logits + segment max.  1 wave/edge, 4/block.
// ---------------------------------------------------------------------------
template <int STOREV>
__global__ __launch_bounds__(256) void edgeA_kernel(
    const float* __restrict__ x_tar, const float* __restrict__ x_tar0,
    const float* __restrict__ x_src, const float* __restrict__ x_src0,
    const float* __restrict__ Rw, const int* __restrict__ edge,
    const float* __restrict__ w_chunk, int e0,
    const float* __restrict__ qW, const float* __restrict__ qW0, const float* __restrict__ qb0,
    const float* __restrict__ kvW, const float* __restrict__ kvW0, const float* __restrict__ kvb0,
    const float* __restrict__ qng, const float* __restrict__ qng0,
    const float* __restrict__ kng, const float* __restrict__ kng0,
    __hip_bfloat16* __restrict__ v_buf, __hip_bfloat16* __restrict__ v0_buf,
    float* __restrict__ logits, unsigned* __restrict__ mx, int E) {
  __shared__ float sR[4][52];
  __shared__ float sT1[4][160];
  __shared__ float sT2[4][160];
  __shared__ float sQ[4][160];
  __shared__ float sQ0[4][32];
  __shared__ float sX0[4][32];
  __shared__ float sKV[4][320];
  __shared__ float sKV0[4][64];
  __shared__ float sY[4][320];
  __shared__ float sY0[4][64];
  const int tid = threadIdx.x;
  const int wv = tid >> 6, w = tid & 63;
  const int e = e0 + blockIdx.x * 4 + wv;
  const int src = edge[e], dst = edge[E + e];

  if (w < 50) sR[wv][w] = Rw[(size_t)e * 50 + w];
  for (int i = w; i < 160; i += 64) sT1[wv][i] = x_tar[(size_t)dst * 160 + i];
  if (w < 32) sX0[wv][w] = x_tar0[(size_t)dst * 32 + w];
  __syncthreads();
  for (int i = w; i < 160; i += 64) {
    int c = i / 10, lm = i % 10, l = lm / 5, m = lm % 5;
    float a = 0.f;
#pragma unroll
    for (int n = 0; n < 5; n++) a += sR[wv][l * 25 + m * 5 + n] * sT1[wv][c * 10 + l * 5 + n];
    sT2[wv][i] = a;
  }
  __syncthreads();
  for (int i = w; i < 160; i += 64) {
    int o = i / 10, lm = i % 10, l = lm / 5, m = lm % 5;
    float a = 0.f;
    const float* wr = qW + l * 256 + o * 16;
#pragma unroll
    for (int c = 0; c < 16; c++) a += wr[c] * sT2[wv][c * 10 + l * 5 + m];
    sQ[wv][i] = a;
  }
  if (w < 32) {
    float a = qb0[w];
    const float* wr = qW0 + w * 32;
#pragma unroll
    for (int c = 0; c < 32; c++) a += wr[c] * sX0[wv][c];
    sQ0[wv][w] = a;
  }
  __syncthreads();
  {
    float p = sQ[wv][w] * sQ[wv][w] + sQ[wv][w + 64] * sQ[wv][w + 64];
    if (w < 32) p += sQ[wv][w + 128] * sQ[wv][w + 128];
    float rms = rsqrtf(waveSum(p) / 160.f + 1e-5f);
    for (int i = w; i < 160; i += 64) sQ[wv][i] *= rms * qng[i / 10];
    float v = (w < 32) ? sQ0[wv][w] : 0.f;
    float s1 = waveSum(v);
    float s2 = waveSum(v * v);
    float mu = s1 / 32.f, var = s2 / 32.f - mu * mu;
    if (w < 32) sQ0[wv][w] = (v - mu) * rsqrtf(var + 1e-5f) * qng0[w];
  }
  __syncthreads();
  for (int i = w; i < 160; i += 64) sT1[wv][i] = x_src[(size_t)src * 160 + i];
  if (w < 32) sX0[wv][w] = x_src0[(size_t)src * 32 + w];
  __syncthreads();
  for (int i = w; i < 160; i += 64) {
    int c = i / 10, lm = i % 10, l = lm / 5, m = lm % 5;
    float a = 0.f;
#pragma unroll
    for (int n = 0; n < 5; n++) a += sR[wv][l * 25 + m * 5 + n] * sT1[wv][c * 10 + l * 5 + n];
    sT2[wv][i] = a;
  }
  __syncthreads();
  for (int i = w; i < 320; i += 64) {
    int o = i / 10, lm = i % 10, l = lm / 5, m = lm % 5;
    float a = 0.f;
    const float* wr = kvW + l * 512 + o * 16;
#pragma unroll
    for (int c = 0; c < 16; c++) a += wr[c] * sT2[wv][c * 10 + l * 5 + m];
    sKV[wv][i] = a;
  }
  {
    float a = kvb0[w];
    const float* wr = kvW0 + w * 32;
#pragma unroll
    for (int c = 0; c < 32; c++) a += wr[c] * sX0[wv][c];
    sKV0[wv][w] = a;
  }
  __syncthreads();
  {
    const float* wa = w_chunk + (size_t)(e - e0) * 384;
    for (int i = w; i < 320; i += 64) {
      int o = i / 10, lm = i % 10, l = lm / 5, m = lm % 5;
      int base = o * 8 + l * 4;
      int xb = o * 10 + l * 5;
      float yv;
      if (m < 2) {
        int j = 1 - m;
        yv = wa[base + 2 + j] * sKV[wv][xb + 3 + j] + wa[base + j] * sKV[wv][xb + 1 - j];
      } else if (m == 2) {
        yv = wa[320 + o * 2 + l] * sKV[wv][xb + 2];
      } else {
        int j = m - 3;
        yv = wa[base + j] * sKV[wv][xb + 3 + j] - wa[base + 2 + j] * sKV[wv][xb + 1 - j];
      }
      sY[wv][i] = yv;
    }
    sY0[wv][w] = wa[256 + w] * sKV0[wv][w];
  }
  __syncthreads();
  {
    float p = sY[wv][w] * sY[wv][w] + sY[wv][w + 64] * sY[wv][w + 64];
    if (w < 32) p += sY[wv][w + 128] * sY[wv][w + 128];
    float rms = rsqrtf(waveSum(p) / 160.f + 1e-5f);
    for (int i = w; i < 160; i += 64) sY[wv][i] *= rms * kng[i / 10];
    float v = (w < 32) ? sY0[wv][w] : 0.f;
    float s1 = waveSum(v);
    float s2 = waveSum(v * v);
    float mu = s1 / 32.f, var = s2 / 32.f - mu * mu;
    if (w < 32) sY0[wv][w] = (v - mu) * rsqrtf(var + 1e-5f) * kng0[w];
  }
  __syncthreads();
  for (int i = w; i < 160; i += 64) sT1[wv][i] = sQ[wv][i] * sY[wv][i];
  if (w < 32) sT2[wv][w] = sQ0[wv][w] * sY0[wv][w];
  if (STOREV) {
    for (int i = w; i < 160; i += 64) v_buf[(size_t)e * 160 + i] = __float2bfloat16(sY[wv][160 + i]);
    if (w < 32) v0_buf[(size_t)e * 32 + w] = __float2bfloat16(sY0[wv][32 + w]);
  }
  __syncthreads();
  if (w < 8) {
    float s = 0.f;
#pragma unroll
    for (int i = 0; i < 20; i++) s += sT1[wv][w * 20 + i];
#pragma unroll
    for (int j = 0; j < 4; j++) s += sT2[wv][w * 4 + j];
    float lg = s * 0.70710678118654752f;
    logits[(size_t)e * 8 + w] = lg;
    atomicMax(&mx[dst * 8 + w], encf(lg));
  }
}

// ---------------------------------------------------------------------------
// Kernel 3: denominator
// ---------------------------------------------------------------------------
__global__ __launch_bounds__(256) void edge2_kernel(
    const int* __restrict__ edge, const float* __restrict__ logits,
    const unsigned* __restrict__ mx, float* __restrict__ den, int E) {
  int idx = blockIdx.x * 256 + threadIdx.x;
  if (idx >= E * 8) return;
  int e = idx >> 3, h = idx & 7;
  int dst = edge[E + e];
  float m = decf(mx[dst * 8 + h]);
  atomicAdd(&den[dst * 8 + h], __expf(logits[idx] - m));
}

// ---------------------------------------------------------------------------
// Kernel 4a (fast): alpha * v (bf16), inverse rotation, scatter-add
// ---------------------------------------------------------------------------
__global__ __launch_bounds__(256) void edgeB_light(
    const float* __restrict__ Rw, const int* __restrict__ edge,
    const __hip_bfloat16* __restrict__ v_buf, const __hip_bfloat16* __restrict__ v0_buf,
    const float* __restrict__ logits, const unsigned* __restrict__ mx,
    const float* __restrict__ den,
    float* __restrict__ att, float* __restrict__ att0, int E) {
  __shared__ float sR[4][52];
  __shared__ float sV[4][160];
  __shared__ float sAl[4][8];
  const int tid = threadIdx.x;
  const int wv = tid >> 6, w = tid & 63;
  const int e = blockIdx.x * 4 + wv;
  const int dst = edge[E + e];
  if (w < 8) {
    float m = decf(mx[dst * 8 + w]);
    sAl[wv][w] = __expf(logits[(size_t)e * 8 + w] - m) / den[dst * 8 + w];
  }
  if (w < 50) sR[wv][w] = Rw[(size_t)e * 50 + w];
  for (int i = w; i < 160; i += 64) sV[wv][i] = __bfloat162float(v_buf[(size_t)e * 160 + i]);
  __syncthreads();
  for (int i = w; i < 160; i += 64) {
    int c = i / 10, lm = i % 10, l = lm / 5, m = lm % 5;
    float a = 0.f;
#pragma unroll
    for (int n = 0; n < 5; n++) a += sR[wv][l * 25 + n * 5 + m] * sV[wv][c * 10 + l * 5 + n];
    atomicAdd(&att[(size_t)dst * 160 + i], sAl[wv][c >> 1] * a);
  }
  if (w < 32)
    atomicAdd(&att0[(size_t)dst * 32 + w], sAl[wv][w >> 2] * __bfloat162float(v0_buf[(size_t)e * 32 + w]));
}

// ---------------------------------------------------------------------------
// Kernel 4b (fallback): recompute v branch from x_src + w_chunk
// ---------------------------------------------------------------------------
__global__ __launch_bounds__(256) void edgeB_rec(
    const float* __restrict__ x_src, const float* __restrict__ x_src0,
    const float* __restrict__ Rw, const int* __restrict__ edge,
    const float* __restrict__ w_chunk, int e0,
    const float* __restrict__ kvW, const float* __restrict__ kvW0, const float* __restrict__ kvb0,
    const float* __restrict__ logits, const unsigned* __restrict__ mx,
    const float* __restrict__ den,
    float* __restrict__ att, float* __restrict__ att0, int E) {
  __shared__ float sR[4][52];
  __shared__ float sT1[4][160];
  __shared__ float sT2[4][160];
  __shared__ float sV[4][160];
  __shared__ float sX0[4][32];
  __shared__ float sAl[4][8];
  const int tid = threadIdx.x;
  const int wv = tid >> 6, w = tid & 63;
  const int e = e0 + blockIdx.x * 4 + wv;
  const int src = edge[e], dst = edge[E + e];
  if (w < 50) sR[wv][w] = Rw[(size_t)e * 50 + w];
  for (int i = w; i < 160; i += 64) sT1[wv][i] = x_src[(size_t)src * 160 + i];
  if (w < 32) sX0[wv][w] = x_src0[(size_t)src * 32 + w];
  if (w < 8) {
    float m = decf(mx[dst * 8 + w]);
    sAl[wv][w] = __expf(logits[(size_t)e * 8 + w] - m) / den[dst * 8 + w];
  }
  __syncthreads();
  for (int i = w; i < 160; i += 64) {
    int c = i / 10, lm = i % 10, l = lm / 5, m = lm % 5;
    float a = 0.f;
#pragma unroll
    for (int n = 0; n < 5; n++) a += sR[wv][l * 25 + m * 5 + n] * sT1[wv][c * 10 + l * 5 + n];
    sT2[wv][i] = a;
  }
  __syncthreads();
  // v-mix: channels o = 16..31 only
  for (int i = w; i < 160; i += 64) {
    int o2 = i / 10, lm = i % 10, l = lm / 5, m = lm % 5;
    float a = 0.f;
    const float* wr = kvW + l * 512 + (16 + o2) * 16;
#pragma unroll
    for (int c = 0; c < 16; c++) a += wr[c] * sT2[wv][c * 10 + l * 5 + m];
    sT1[wv][i] = a;  // reuse as v-mix
  }
  float kv0v = 0.f;
  if (w < 32) {
    kv0v = kvb0[32 + w];
    const float* wr = kvW0 + (32 + w) * 32;
#pragma unroll
    for (int c = 0; c < 32; c++) kv0v += wr[c] * sX0[wv][c];
  }
  __syncthreads();
  {
    const float* wa = w_chunk + (size_t)(e - e0) * 384;
    for (int i = w; i < 160; i += 64) {
      int o2 = i / 10, lm = i % 10, l = lm / 5, m = lm % 5;
      int o = 16 + o2;
      int base = o * 8 + l * 4;
      int xb = o2 * 10 + l * 5;
      float yv;
      if (m < 2) {
        int j = 1 - m;
        yv = wa[base + 2 + j] * sT1[wv][xb + 3 + j] + wa[base + j] * sT1[wv][xb + 1 - j];
      } else if (m == 2) {
        yv = wa[320 + o * 2 + l] * sT1[wv][xb + 2];
      } else {
        int j = m - 3;
        yv = wa[base + j] * sT1[wv][xb + 3 + j] - wa[base + 2 + j] * sT1[wv][xb + 1 - j];
      }
      sV[wv][i] = yv;
    }
    if (w < 32) kv0v *= wa[256 + 32 + w];
  }
  __syncthreads();
  for (int i = w; i < 160; i += 64) {
    int c = i / 10, lm = i % 10, l = lm / 5, m = lm % 5;
    float a = 0.f;
#pragma unroll
    for (int n = 0; n < 5; n++) a += sR[wv][l * 25 + n * 5 + m] * sV[wv][c * 10 + l * 5 + n];
    atomicAdd(&att[(size_t)dst * 160 + i], sAl[wv][c >> 1] * a);
  }
  if (w < 32) atomicAdd(&att0[(size_t)dst * 32 + w], sAl[wv][w >> 2] * kv0v);
}

// ---------------------------------------------------------------------------
// Kernel 5: per-node output projection, in place over d_out
// ---------------------------------------------------------------------------
__global__ __launch_bounds__(256) void node_kernel(
    const float* __restrict__ pW, const float* __restrict__ pW0,
    const float* __restrict__ pb0, float* __restrict__ out, int N) {
  __shared__ float sA[4][160];
  __shared__ float sA0[4][32];
  const int tid = threadIdx.x;
  const int wv = tid >> 6, w = tid & 63;
  const int n = blockIdx.x * 4 + wv;
  if (n < N) {
    for (int i = w; i < 160; i += 64) sA[wv][i] = out[(size_t)n * 160 + i];
    if (w < 32) sA0[wv][w] = out[(size_t)N * 160 + (size_t)n * 32 + w];
  }
  __syncthreads();
  if (n >= N) return;
  for (int i = w; i < 160; i += 64) {
    int o = i / 10, lm = i % 10, l = lm / 5, m = lm % 5;
    float a = 0.f;
    const float* wr = pW + l * 256 + o * 16;
#pragma unroll
    for (int c = 0; c < 16; c++) a += wr[c] * sA[wv][c * 10 + l * 5 + m];
    out[(size_t)n * 160 + i] = a;
  }
  if (w < 32) {
    float a = pb0[w];
    const float* wr = pW0 + w * 32;
#pragma unroll
    for (int c = 0; c < 32; c++) a += wr[c] * sA0[wv][c];
    out[(size_t)N * 160 + (size_t)n * 32 + w] = a;
  }
}

// ---------------------------------------------------------------------------
extern "C" void kernel_launch(void* const* d_in, const int* in_sizes, int n_in,
                              void* d_out, int out_size, void* d_ws, size_t ws_size,
                              hipStream_t stream) {
  const float* x_src  = (const float*)d_in[0];
  const float* x_tar  = (const float*)d_in[1];
  const float* x_src0 = (const float*)d_in[2];
  const float* x_tar0 = (const float*)d_in[3];
  const float* Rw     = (const float*)d_in[4];
  const float* ef     = (const float*)d_in[5];
  const int*   edge   = (const int*)d_in[6];
  const float* r_W1 = (const float*)d_in[10];
  const float* r_b1 = (const float*)d_in[11];
  const float* r_g1 = (const float*)d_in[12];
  const float* r_be1 = (const float*)d_in[13];
  const float* r_W2 = (const float*)d_in[14];
  const float* r_b2 = (const float*)d_in[15];
  const float* r_g2 = (const float*)d_in[16];
  const float* r_be2 = (const float*)d_in[17];
  const float* r_W3 = (const float*)d_in[18];
  const float* r_b3 = (const float*)d_in[19];
  const float* qW  = (const float*)d_in[20];
  const float* qW0 = (const float*)d_in[21];
  const float* qb0 = (const float*)d_in[22];
  const float* kvW  = (const float*)d_in[23];
  const float* kvW0 = (const float*)d_in[24];
  const float* kvb0 = (const float*)d_in[25];
  const float* qng  = (const float*)d_in[26];
  const float* qng0 = (const float*)d_in[27];
  const float* kng  = (const float*)d_in[28];
  const float* kng0 = (const float*)d_in[29];
  const float* pW  = (const float*)d_in[30];
  const float* pW0 = (const float*)d_in[31];
  const float* pb0 = (const float*)d_in[32];

  const int N = in_sizes[0] / 160;   // 10000
  const int E = in_sizes[4] / 50;    // 160000
  float* out = (float*)d_out;

  char* ws = (char*)d_ws;
  size_t off = 0;
  float* logits = (float*)(ws + off); off += (size_t)E * 8 * 4;
  size_t zoff = off;
  unsigned* mxb = (unsigned*)(ws + off); off += (size_t)N * 8 * 4;
  float* den = (float*)(ws + off); off += (size_t)N * 8 * 4;
  size_t zend = off;

  if (ws_size <= off + 32 * 384 * 4) return;  // hopeless (needs ~6 MB)
  size_t avail = ws_size - off;
  const size_t vsz = (size_t)E * 160 * 2 + (size_t)E * 32 * 2;
  bool fast = false;
  size_t CE;
  __hip_bfloat16 *vb = nullptr, *v0b = nullptr;
  if (avail >= vsz + (size_t)1024 * 384 * 4) {
    fast = true;
    vb  = (__hip_bfloat16*)(ws + off); off += (size_t)E * 160 * 2;
    v0b = (__hip_bfloat16*)(ws + off); off += (size_t)E * 32 * 2;
    CE = (ws_size - off) / (384 * 4);
  } else {
    CE = avail / (384 * 4);
  }
  if (CE > (size_t)E) CE = E;
  CE &= ~(size_t)31;
  if (CE == 0) return;
  float* w_chunk = (float*)(ws + off);

  hipMemsetAsync(ws + zoff, 0, zend - zoff, stream);
  hipMemsetAsync(d_out, 0, (size_t)out_size * 4, stream);

  for (int e0 = 0; e0 < E; e0 += (int)CE) {
    int cnt = E - e0 < (int)CE ? E - e0 : (int)CE;
    radial_kernel<<<cnt / 32, 256, 0, stream>>>(ef, r_W1, r_b1, r_g1, r_be1,
                                                r_W2, r_b2, r_g2, r_be2, r_W3, r_b3,
                                                w_chunk, e0);
    if (fast)
      edgeA_kernel<1><<<cnt / 4, 256, 0, stream>>>(x_tar, x_tar0, x_src, x_src0, Rw, edge,
                                                   w_chunk, e0, qW, qW0, qb0, kvW, kvW0, kvb0,
                                                   qng, qng0, kng, kng0, vb, v0b, logits, mxb, E);
    else
      edgeA_kernel<0><<<cnt / 4, 256, 0, stream>>>(x_tar, x_tar0, x_src, x_src0, Rw, edge,
                                                   w_chunk, e0, qW, qW0, qb0, kvW, kvW0, kvb0,
                                                   qng, qng0, kng, kng0, vb, v0b, logits, mxb, E);
  }
  edge2_kernel<<<(E * 8 + 255) / 256, 256, 0, stream>>>(edge, logits, mxb, den, E);
  float* att  = out;
  float* att0 = out + (size_t)N * 160;
  if (fast) {
    edgeB_light<<<E / 4, 256, 0, stream>>>(Rw, edge, vb, v0b, logits, mxb, den, att, att0, E);
  } else {
    for (int e0 = 0; e0 < E; e0 += (int)CE) {
      int cnt = E - e0 < (int)CE ? E - e0 : (int)CE;
      radial_kernel<<<cnt / 32, 256, 0, stream>>>(ef, r_W1, r_b1, r_g1, r_be1,
                                                  r_W2, r_b2, r_g2, r_be2, r_W3, r_b3,
                                                  w_chunk, e0);
      edgeB_rec<<<cnt / 4, 256, 0, stream>>>(x_src, x_src0, Rw, edge, w_chunk, e0,
                                             kvW, kvW0, kvb0, logits, mxb, den, att, att0, E);
    }
  }
  node_kernel<<<(N + 3) / 4, 256, 0, stream>>>(pW, pW0, pb0, out, N);
}

// Round 3
// 1032.503 us; speedup vs baseline: 1.5887x; 1.5887x over previous
//
#include <hip/hip_runtime.h>
#include <hip/hip_bf16.h>
#include <math.h>

// N=10000, E=160000, C=16, C0=32, L=2, M=5, H=8, R_IN=32, R_HID=128, REQ=384

typedef short bf16x8 __attribute__((ext_vector_type(8)));
typedef float f32x4 __attribute__((ext_vector_type(4)));

__device__ __forceinline__ float waveSum(float v) {
#pragma unroll
  for (int m = 1; m < 64; m <<= 1) v += __shfl_xor(v, m, 64);
  return v;
}
__device__ __forceinline__ unsigned encf(float f) {
  unsigned u = __float_as_uint(f);
  return (u & 0x80000000u) ? ~u : (u | 0x80000000u);
}
__device__ __forceinline__ float decf(unsigned u) {
  return (u & 0x80000000u) ? __uint_as_float(u & 0x7FFFFFFFu) : __uint_as_float(~u);
}
__device__ __forceinline__ unsigned short f2bu(float f) {
  __hip_bfloat16 h = __float2bfloat16(f);
  unsigned short u;
  __builtin_memcpy(&u, &h, 2);
  return u;
}

// ---------------------------------------------------------------------------
// Prep: transpose radial weights to bf16 [n][k] layout (runs once per launch)
// W1T: [128][32], W2T: [128][128], W3T: [384][128]
// ---------------------------------------------------------------------------
__global__ __launch_bounds__(256) void prep_kernel(
    const float* __restrict__ W1, const float* __restrict__ W2,
    const float* __restrict__ W3,
    unsigned short* __restrict__ W1T, unsigned short* __restrict__ W2T,
    unsigned short* __restrict__ W3T) {
  int idx = blockIdx.x * 256 + threadIdx.x;
  if (idx < 128 * 32) {
    int n = idx >> 5, k = idx & 31;
    W1T[idx] = f2bu(W1[k * 128 + n]);
  }
  int i2 = idx - 128 * 32;
  if (i2 >= 0 && i2 < 128 * 128) {
    int n = i2 >> 7, k = i2 & 127;
    W2T[i2] = f2bu(W2[k * 128 + n]);
  }
  int i3 = idx - 128 * 32 - 128 * 128;
  if (i3 >= 0 && i3 < 384 * 128) {
    int n = i3 >> 7, k = i3 & 127;
    W3T[i3] = f2bu(W3[k * 384 + n]);
  }
}

// ---------------------------------------------------------------------------
// Kernel 1: MFMA radial MLP. 128 edges / 256-thread block (4 waves).
// LDS: sA (activations, bf16 128x128) + sW (weight tile, bf16 128x128),
// both XOR-swizzled: byte = row*256 + (k*2 ^ ((row&7)<<4)).
// mfma_f32_16x16x32_bf16: A lane l: row=l&15, k=(l>>4)*8+j ; B: col=l&15, same k.
// C/D: col=lane&15, row=(lane>>4)*4+reg.
// ---------------------------------------------------------------------------
__global__ __launch_bounds__(256) void radial_mfma(
    const float* __restrict__ ef,
    const unsigned short* __restrict__ W1T, const unsigned short* __restrict__ W2T,
    const unsigned short* __restrict__ W3T,
    const float* __restrict__ b1, const float* __restrict__ g1, const float* __restrict__ be1,
    const float* __restrict__ b2, const float* __restrict__ g2, const float* __restrict__ be2,
    const float* __restrict__ b3,
    float* __restrict__ w_chunk, int e0, int E) {
  __shared__ unsigned short sA[128 * 128];
  __shared__ unsigned short sW[128 * 128];
  const int tid = threadIdx.x;
  const int lane = tid & 63, wid = tid >> 6;
  const int eb = blockIdx.x * 128;
  const int colq = lane & 15, rowq = lane >> 4;

  // per-lane column params (col = nt*16 + colq)
  float b1v[8], g1v[8], be1v[8], b2v[8], g2v[8], be2v[8];
#pragma unroll
  for (int nt = 0; nt < 8; nt++) {
    int c = nt * 16 + colq;
    b1v[nt] = b1[c]; g1v[nt] = g1[c]; be1v[nt] = be1[c];
    b2v[nt] = b2[c]; g2v[nt] = g2[c]; be2v[nt] = be2[c];
  }

  // stage ef (128 x 32 f32 -> bf16)
  for (int idx = tid; idx < 1024; idx += 256) {
    int e = idx >> 3, k4 = idx & 7;
    int ee = e0 + eb + e; if (ee >= E) ee = E - 1;
    float4 v = *(const float4*)&ef[(size_t)ee * 32 + k4 * 4];
    ushort4 uu = make_ushort4(f2bu(v.x), f2bu(v.y), f2bu(v.z), f2bu(v.w));
    unsigned bo = (unsigned)e * 256 + (((unsigned)k4 * 8) ^ ((e & 7) << 4));
    *(ushort4*)((char*)sA + bo) = uu;
  }
  // stage W1T (128 rows x 64B)
  for (int idx = tid; idx < 512; idx += 256) {
    int n = idx >> 2, j = idx & 3;
    uint4 v = *(const uint4*)&W1T[n * 32 + j * 8];
    unsigned bo = (unsigned)n * 256 + (((unsigned)j * 16) ^ ((n & 7) << 4));
    *(uint4*)((char*)sW + bo) = v;
  }
  __syncthreads();

  f32x4 zz = {0.f, 0.f, 0.f, 0.f};
  f32x4 acc[2][8];
#pragma unroll
  for (int mt = 0; mt < 2; mt++)
#pragma unroll
    for (int nt = 0; nt < 8; nt++) acc[mt][nt] = zz;

  // ---- L1: K=32 (one k-step) ----
  {
    bf16x8 af[2];
#pragma unroll
    for (int mt = 0; mt < 2; mt++) {
      int row = wid * 32 + mt * 16 + colq;
      unsigned bo = (unsigned)row * 256 + (((unsigned)rowq * 16) ^ ((row & 7) << 4));
      af[mt] = *(const bf16x8*)((const char*)sA + bo);
    }
#pragma unroll
    for (int nt = 0; nt < 8; nt++) {
      int n = nt * 16 + colq;
      unsigned bo = (unsigned)n * 256 + (((unsigned)rowq * 16) ^ ((n & 7) << 4));
      bf16x8 bfv = *(const bf16x8*)((const char*)sW + bo);
#pragma unroll
      for (int mt = 0; mt < 2; mt++)
        acc[mt][nt] = __builtin_amdgcn_mfma_f32_16x16x32_bf16(af[mt], bfv, acc[mt][nt], 0, 0, 0);
    }
  }
  __syncthreads();  // all waves done reading sA/sW for L1

  // ---- LN + silu on h1, write bf16 to sA; stage W2T concurrently ----
#pragma unroll
  for (int mt = 0; mt < 2; mt++) {
#pragma unroll
    for (int r = 0; r < 4; r++) {
      float s1 = 0.f, s2 = 0.f;
#pragma unroll
      for (int nt = 0; nt < 8; nt++) {
        float v = acc[mt][nt][r] + b1v[nt];
        s1 += v; s2 += v * v;
      }
#pragma unroll
      for (int off = 1; off < 16; off <<= 1) { s1 += __shfl_xor(s1, off, 64); s2 += __shfl_xor(s2, off, 64); }
      float mu = s1 * (1.f / 128.f);
      float rs = rsqrtf(s2 * (1.f / 128.f) - mu * mu + 1e-5f);
      int row = wid * 32 + mt * 16 + rowq * 4 + r;
      unsigned rbase = (unsigned)row * 256;
      unsigned swz = (row & 7) << 4;
#pragma unroll
      for (int nt = 0; nt < 8; nt++) {
        float v = (acc[mt][nt][r] + b1v[nt] - mu) * rs * g1v[nt] + be1v[nt];
        v = v / (1.f + __expf(-v));
        *(unsigned short*)((char*)sA + rbase + ((((unsigned)(nt * 16 + colq)) * 2) ^ swz)) = f2bu(v);
      }
    }
  }
  for (int idx = tid; idx < 2048; idx += 256) {
    int n = idx >> 4, j = idx & 15;
    uint4 v = *(const uint4*)&W2T[n * 128 + j * 8];
    unsigned bo = (unsigned)n * 256 + (((unsigned)j * 16) ^ ((n & 7) << 4));
    *(uint4*)((char*)sW + bo) = v;
  }
  __syncthreads();

  // ---- L2: K=128 ----
#pragma unroll
  for (int mt = 0; mt < 2; mt++)
#pragma unroll
    for (int nt = 0; nt < 8; nt++) acc[mt][nt] = zz;
#pragma unroll
  for (int ks = 0; ks < 4; ks++) {
    bf16x8 af[2];
#pragma unroll
    for (int mt = 0; mt < 2; mt++) {
      int row = wid * 32 + mt * 16 + colq;
      unsigned bo = (unsigned)row * 256 + (((unsigned)(ks * 64 + rowq * 16)) ^ ((row & 7) << 4));
      af[mt] = *(const bf16x8*)((const char*)sA + bo);
    }
#pragma unroll
    for (int nt = 0; nt < 8; nt++) {
      int n = nt * 16 + colq;
      unsigned bo = (unsigned)n * 256 + (((unsigned)(ks * 64 + rowq * 16)) ^ ((n & 7) << 4));
      bf16x8 bfv = *(const bf16x8*)((const char*)sW + bo);
#pragma unroll
      for (int mt = 0; mt < 2; mt++)
        acc[mt][nt] = __builtin_amdgcn_mfma_f32_16x16x32_bf16(af[mt], bfv, acc[mt][nt], 0, 0, 0);
    }
  }
  __syncthreads();  // all waves done reading sA (h1) / sW (W2)

  // ---- LN + silu on h2, write bf16 to sA ----
#pragma unroll
  for (int mt = 0; mt < 2; mt++) {
#pragma unroll
    for (int r = 0; r < 4; r++) {
      float s1 = 0.f, s2 = 0.f;
#pragma unroll
      for (int nt = 0; nt < 8; nt++) {
        float v = acc[mt][nt][r] + b2v[nt];
        s1 += v; s2 += v * v;
      }
#pragma unroll
      for (int off = 1; off < 16; off <<= 1) { s1 += __shfl_xor(s1, off, 64); s2 += __shfl_xor(s2, off, 64); }
      float mu = s1 * (1.f / 128.f);
      float rs = rsqrtf(s2 * (1.f / 128.f) - mu * mu + 1e-5f);
      int row = wid * 32 + mt * 16 + rowq * 4 + r;
      unsigned rbase = (unsigned)row * 256;
      unsigned swz = (row & 7) << 4;
#pragma unroll
      for (int nt = 0; nt < 8; nt++) {
        float v = (acc[mt][nt][r] + b2v[nt] - mu) * rs * g2v[nt] + be2v[nt];
        v = v / (1.f + __expf(-v));
        *(unsigned short*)((char*)sA + rbase + ((((unsigned)(nt * 16 + colq)) * 2) ^ swz)) = f2bu(v);
      }
    }
  }

  // ---- L3: 3 chunks of 128 cols ----
  for (int cc = 0; cc < 3; cc++) {
    if (cc > 0) __syncthreads();  // prior chunk's MFMA reads of sW done
    for (int idx = tid; idx < 2048; idx += 256) {
      int n = idx >> 4, j = idx & 15;
      uint4 v = *(const uint4*)&W3T[(size_t)(cc * 128 + n) * 128 + j * 8];
      unsigned bo = (unsigned)n * 256 + (((unsigned)j * 16) ^ ((n & 7) << 4));
      *(uint4*)((char*)sW + bo) = v;
    }
    __syncthreads();
    f32x4 a3[2][8];
#pragma unroll
    for (int mt = 0; mt < 2; mt++)
#pragma unroll
      for (int nt = 0; nt < 8; nt++) a3[mt][nt] = zz;
#pragma unroll
    for (int ks = 0; ks < 4; ks++) {
      bf16x8 af[2];
#pragma unroll
      for (int mt = 0; mt < 2; mt++) {
        int row = wid * 32 + mt * 16 + colq;
        unsigned bo = (unsigned)row * 256 + (((unsigned)(ks * 64 + rowq * 16)) ^ ((row & 7) << 4));
        af[mt] = *(const bf16x8*)((const char*)sA + bo);
      }
#pragma unroll
      for (int nt = 0; nt < 8; nt++) {
        int n = nt * 16 + colq;
        unsigned bo = (unsigned)n * 256 + (((unsigned)(ks * 64 + rowq * 16)) ^ ((n & 7) << 4));
        bf16x8 bfv = *(const bf16x8*)((const char*)sW + bo);
#pragma unroll
        for (int mt = 0; mt < 2; mt++)
          a3[mt][nt] = __builtin_amdgcn_mfma_f32_16x16x32_bf16(af[mt], bfv, a3[mt][nt], 0, 0, 0);
      }
    }
#pragma unroll
    for (int nt = 0; nt < 8; nt++) {
      int col = cc * 128 + nt * 16 + colq;
      float b3v = b3[col];
#pragma unroll
      for (int mt = 0; mt < 2; mt++) {
#pragma unroll
        for (int r = 0; r < 4; r++) {
          int row_e = eb + wid * 32 + mt * 16 + rowq * 4 + r;
          w_chunk[(size_t)row_e * 384 + col] = a3[mt][nt][r] + b3v;
        }
      }
    }
  }
}

// ---------------------------------------------------------------------------
// Kernel 2: per-edge q/k(/v) + logits + segment max.  1 wave/edge, 4/block.
// ---------------------------------------------------------------------------
template <int STOREV>
__global__ __launch_bounds__(256) void edgeA_kernel(
    const float* __restrict__ x_tar, const float* __restrict__ x_tar0,
    const float* __restrict__ x_src, const float* __restrict__ x_src0,
    const float* __restrict__ Rw, const int* __restrict__ edge,
    const float* __restrict__ w_chunk, int e0,
    const float* __restrict__ qW, const float* __restrict__ qW0, const float* __restrict__ qb0,
    const float* __restrict__ kvW, const float* __restrict__ kvW0, const float* __restrict__ kvb0,
    const float* __restrict__ qng, const float* __restrict__ qng0,
    const float* __restrict__ kng, const float* __restrict__ kng0,
    __hip_bfloat16* __restrict__ v_buf, __hip_bfloat16* __restrict__ v0_buf,
    float* __restrict__ logits, unsigned* __restrict__ mx, int E) {
  __shared__ float sR[4][52];
  __shared__ float sT1[4][160];
  __shared__ float sT2[4][160];
  __shared__ float sQ[4][160];
  __shared__ float sQ0[4][32];
  __shared__ float sX0[4][32];
  __shared__ float sKV[4][320];
  __shared__ float sKV0[4][64];
  __shared__ float sY[4][320];
  __shared__ float sY0[4][64];
  const int tid = threadIdx.x;
  const int wv = tid >> 6, w = tid & 63;
  const int e = e0 + blockIdx.x * 4 + wv;
  const int src = edge[e], dst = edge[E + e];

  if (w < 50) sR[wv][w] = Rw[(size_t)e * 50 + w];
  for (int i = w; i < 160; i += 64) sT1[wv][i] = x_tar[(size_t)dst * 160 + i];
  if (w < 32) sX0[wv][w] = x_tar0[(size_t)dst * 32 + w];
  __syncthreads();
  for (int i = w; i < 160; i += 64) {
    int c = i / 10, lm = i % 10, l = lm / 5, m = lm % 5;
    float a = 0.f;
#pragma unroll
    for (int n = 0; n < 5; n++) a += sR[wv][l * 25 + m * 5 + n] * sT1[wv][c * 10 + l * 5 + n];
    sT2[wv][i] = a;
  }
  __syncthreads();
  for (int i = w; i < 160; i += 64) {
    int o = i / 10, lm = i % 10, l = lm / 5, m = lm % 5;
    float a = 0.f;
    const float* wr = qW + l * 256 + o * 16;
#pragma unroll
    for (int c = 0; c < 16; c++) a += wr[c] * sT2[wv][c * 10 + l * 5 + m];
    sQ[wv][i] = a;
  }
  if (w < 32) {
    float a = qb0[w];
    const float* wr = qW0 + w * 32;
#pragma unroll
    for (int c = 0; c < 32; c++) a += wr[c] * sX0[wv][c];
    sQ0[wv][w] = a;
  }
  __syncthreads();
  {
    float p = sQ[wv][w] * sQ[wv][w] + sQ[wv][w + 64] * sQ[wv][w + 64];
    if (w < 32) p += sQ[wv][w + 128] * sQ[wv][w + 128];
    float rms = rsqrtf(waveSum(p) / 160.f + 1e-5f);
    for (int i = w; i < 160; i += 64) sQ[wv][i] *= rms * qng[i / 10];
    float v = (w < 32) ? sQ0[wv][w] : 0.f;
    float s1 = waveSum(v);
    float s2 = waveSum(v * v);
    float mu = s1 / 32.f, var = s2 / 32.f - mu * mu;
    if (w < 32) sQ0[wv][w] = (v - mu) * rsqrtf(var + 1e-5f) * qng0[w];
  }
  __syncthreads();
  for (int i = w; i < 160; i += 64) sT1[wv][i] = x_src[(size_t)src * 160 + i];
  if (w < 32) sX0[wv][w] = x_src0[(size_t)src * 32 + w];
  __syncthreads();
  for (int i = w; i < 160; i += 64) {
    int c = i / 10, lm = i % 10, l = lm / 5, m = lm % 5;
    float a = 0.f;
#pragma unroll
    for (int n = 0; n < 5; n++) a += sR[wv][l * 25 + m * 5 + n] * sT1[wv][c * 10 + l * 5 + n];
    sT2[wv][i] = a;
  }
  __syncthreads();
  for (int i = w; i < 320; i += 64) {
    int o = i / 10, lm = i % 10, l = lm / 5, m = lm % 5;
    float a = 0.f;
    const float* wr = kvW + l * 512 + o * 16;
#pragma unroll
    for (int c = 0; c < 16; c++) a += wr[c] * sT2[wv][c * 10 + l * 5 + m];
    sKV[wv][i] = a;
  }
  {
    float a = kvb0[w];
    const float* wr = kvW0 + w * 32;
#pragma unroll
    for (int c = 0; c < 32; c++) a += wr[c] * sX0[wv][c];
    sKV0[wv][w] = a;
  }
  __syncthreads();
  {
    const float* wa = w_chunk + (size_t)(e - e0) * 384;
    for (int i = w; i < 320; i += 64) {
      int o = i / 10, lm = i % 10, l = lm / 5, m = lm % 5;
      int base = o * 8 + l * 4;
      int xb = o * 10 + l * 5;
      float yv;
      if (m < 2) {
        int j = 1 - m;
        yv = wa[base + 2 + j] * sKV[wv][xb + 3 + j] + wa[base + j] * sKV[wv][xb + 1 - j];
      } else if (m == 2) {
        yv = wa[320 + o * 2 + l] * sKV[wv][xb + 2];
      } else {
        int j = m - 3;
        yv = wa[base + j] * sKV[wv][xb + 3 + j] - wa[base + 2 + j] * sKV[wv][xb + 1 - j];
      }
      sY[wv][i] = yv;
    }
    sY0[wv][w] = wa[256 + w] * sKV0[wv][w];
  }
  __syncthreads();
  {
    float p = sY[wv][w] * sY[wv][w] + sY[wv][w + 64] * sY[wv][w + 64];
    if (w < 32) p += sY[wv][w + 128] * sY[wv][w + 128];
    float rms = rsqrtf(waveSum(p) / 160.f + 1e-5f);
    for (int i = w; i < 160; i += 64) sY[wv][i] *= rms * kng[i / 10];
    float v = (w < 32) ? sY0[wv][w] : 0.f;
    float s1 = waveSum(v);
    float s2 = waveSum(v * v);
    float mu = s1 / 32.f, var = s2 / 32.f - mu * mu;
    if (w < 32) sY0[wv][w] = (v - mu) * rsqrtf(var + 1e-5f) * kng0[w];
  }
  __syncthreads();
  for (int i = w; i < 160; i += 64) sT1[wv][i] = sQ[wv][i] * sY[wv][i];
  if (w < 32) sT2[wv][w] = sQ0[wv][w] * sY0[wv][w];
  if (STOREV) {
    for (int i = w; i < 160; i += 64) v_buf[(size_t)e * 160 + i] = __float2bfloat16(sY[wv][160 + i]);
    if (w < 32) v0_buf[(size_t)e * 32 + w] = __float2bfloat16(sY0[wv][32 + w]);
  }
  __syncthreads();
  if (w < 8) {
    float s = 0.f;
#pragma unroll
    for (int i = 0; i < 20; i++) s += sT1[wv][w * 20 + i];
#pragma unroll
    for (int j = 0; j < 4; j++) s += sT2[wv][w * 4 + j];
    float lg = s * 0.70710678118654752f;
    logits[(size_t)e * 8 + w] = lg;
    atomicMax(&mx[dst * 8 + w], encf(lg));
  }
}

// ---------------------------------------------------------------------------
// Kernel 3: denominator
// ---------------------------------------------------------------------------
__global__ __launch_bounds__(256) void edge2_kernel(
    const int* __restrict__ edge, const float* __restrict__ logits,
    const unsigned* __restrict__ mx, float* __restrict__ den, int E) {
  int idx = blockIdx.x * 256 + threadIdx.x;
  if (idx >= E * 8) return;
  int e = idx >> 3, h = idx & 7;
  int dst = edge[E + e];
  float m = decf(mx[dst * 8 + h]);
  atomicAdd(&den[dst * 8 + h], __expf(logits[idx] - m));
}

// ---------------------------------------------------------------------------
// Kernel 4a (fast): alpha * v (bf16), inverse rotation, scatter-add
// ---------------------------------------------------------------------------
__global__ __launch_bounds__(256) void edgeB_light(
    const float* __restrict__ Rw, const int* __restrict__ edge,
    const __hip_bfloat16* __restrict__ v_buf, const __hip_bfloat16* __restrict__ v0_buf,
    const float* __restrict__ logits, const unsigned* __restrict__ mx,
    const float* __restrict__ den,
    float* __restrict__ att, float* __restrict__ att0, int E) {
  __shared__ float sR[4][52];
  __shared__ float sV[4][160];
  __shared__ float sAl[4][8];
  const int tid = threadIdx.x;
  const int wv = tid >> 6, w = tid & 63;
  const int e = blockIdx.x * 4 + wv;
  const int dst = edge[E + e];
  if (w < 8) {
    float m = decf(mx[dst * 8 + w]);
    sAl[wv][w] = __expf(logits[(size_t)e * 8 + w] - m) / den[dst * 8 + w];
  }
  if (w < 50) sR[wv][w] = Rw[(size_t)e * 50 + w];
  for (int i = w; i < 160; i += 64) sV[wv][i] = __bfloat162float(v_buf[(size_t)e * 160 + i]);
  __syncthreads();
  for (int i = w; i < 160; i += 64) {
    int c = i / 10, lm = i % 10, l = lm / 5, m = lm % 5;
    float a = 0.f;
#pragma unroll
    for (int n = 0; n < 5; n++) a += sR[wv][l * 25 + n * 5 + m] * sV[wv][c * 10 + l * 5 + n];
    atomicAdd(&att[(size_t)dst * 160 + i], sAl[wv][c >> 1] * a);
  }
  if (w < 32)
    atomicAdd(&att0[(size_t)dst * 32 + w], sAl[wv][w >> 2] * __bfloat162float(v0_buf[(size_t)e * 32 + w]));
}

// ---------------------------------------------------------------------------
// Kernel 4b (fallback): recompute v branch from x_src + w_chunk
// ---------------------------------------------------------------------------
__global__ __launch_bounds__(256) void edgeB_rec(
    const float* __restrict__ x_src, const float* __restrict__ x_src0,
    const float* __restrict__ Rw, const int* __restrict__ edge,
    const float* __restrict__ w_chunk, int e0,
    const float* __restrict__ kvW, const float* __restrict__ kvW0, const float* __restrict__ kvb0,
    const float* __restrict__ logits, const unsigned* __restrict__ mx,
    const float* __restrict__ den,
    float* __restrict__ att, float* __restrict__ att0, int E) {
  __shared__ float sR[4][52];
  __shared__ float sT1[4][160];
  __shared__ float sT2[4][160];
  __shared__ float sV[4][160];
  __shared__ float sX0[4][32];
  __shared__ float sAl[4][8];
  const int tid = threadIdx.x;
  const int wv = tid >> 6, w = tid & 63;
  const int e = e0 + blockIdx.x * 4 + wv;
  const int src = edge[e], dst = edge[E + e];
  if (w < 50) sR[wv][w] = Rw[(size_t)e * 50 + w];
  for (int i = w; i < 160; i += 64) sT1[wv][i] = x_src[(size_t)src * 160 + i];
  if (w < 32) sX0[wv][w] = x_src0[(size_t)src * 32 + w];
  if (w < 8) {
    float m = decf(mx[dst * 8 + w]);
    sAl[wv][w] = __expf(logits[(size_t)e * 8 + w] - m) / den[dst * 8 + w];
  }
  __syncthreads();
  for (int i = w; i < 160; i += 64) {
    int c = i / 10, lm = i % 10, l = lm / 5, m = lm % 5;
    float a = 0.f;
#pragma unroll
    for (int n = 0; n < 5; n++) a += sR[wv][l * 25 + m * 5 + n] * sT1[wv][c * 10 + l * 5 + n];
    sT2[wv][i] = a;
  }
  __syncthreads();
  for (int i = w; i < 160; i += 64) {
    int o2 = i / 10, lm = i % 10, l = lm / 5, m = lm % 5;
    float a = 0.f;
    const float* wr = kvW + l * 512 + (16 + o2) * 16;
#pragma unroll
    for (int c = 0; c < 16; c++) a += wr[c] * sT2[wv][c * 10 + l * 5 + m];
    sT1[wv][i] = a;
  }
  float kv0v = 0.f;
  if (w < 32) {
    kv0v = kvb0[32 + w];
    const float* wr = kvW0 + (32 + w) * 32;
#pragma unroll
    for (int c = 0; c < 32; c++) kv0v += wr[c] * sX0[wv][c];
  }
  __syncthreads();
  {
    const float* wa = w_chunk + (size_t)(e - e0) * 384;
    for (int i = w; i < 160; i += 64) {
      int o2 = i / 10, lm = i % 10, l = lm / 5, m = lm % 5;
      int o = 16 + o2;
      int base = o * 8 + l * 4;
      int xb = o2 * 10 + l * 5;
      float yv;
      if (m < 2) {
        int j = 1 - m;
        yv = wa[base + 2 + j] * sT1[wv][xb + 3 + j] + wa[base + j] * sT1[wv][xb + 1 - j];
      } else if (m == 2) {
        yv = wa[320 + o * 2 + l] * sT1[wv][xb + 2];
      } else {
        int j = m - 3;
        yv = wa[base + j] * sT1[wv][xb + 3 + j] - wa[base + 2 + j] * sT1[wv][xb + 1 - j];
      }
      sV[wv][i] = yv;
    }
    if (w < 32) kv0v *= wa[256 + 32 + w];
  }
  __syncthreads();
  for (int i = w; i < 160; i += 64) {
    int c = i / 10, lm = i % 10, l = lm / 5, m = lm % 5;
    float a = 0.f;
#pragma unroll
    for (int n = 0; n < 5; n++) a += sR[wv][l * 25 + n * 5 + m] * sV[wv][c * 10 + l * 5 + n];
    atomicAdd(&att[(size_t)dst * 160 + i], sAl[wv][c >> 1] * a);
  }
  if (w < 32) atomicAdd(&att0[(size_t)dst * 32 + w], sAl[wv][w >> 2] * kv0v);
}

// ---------------------------------------------------------------------------
// Kernel 5: per-node output projection, in place over d_out
// ---------------------------------------------------------------------------
__global__ __launch_bounds__(256) void node_kernel(
    const float* __restrict__ pW, const float* __restrict__ pW0,
    const float* __restrict__ pb0, float* __restrict__ out, int N) {
  __shared__ float sA[4][160];
  __shared__ float sA0[4][32];
  const int tid = threadIdx.x;
  const int wv = tid >> 6, w = tid & 63;
  const int n = blockIdx.x * 4 + wv;
  if (n < N) {
    for (int i = w; i < 160; i += 64) sA[wv][i] = out[(size_t)n * 160 + i];
    if (w < 32) sA0[wv][w] = out[(size_t)N * 160 + (size_t)n * 32 + w];
  }
  __syncthreads();
  if (n >= N) return;
  for (int i = w; i < 160; i += 64) {
    int o = i / 10, lm = i % 10, l = lm / 5, m = lm % 5;
    float a = 0.f;
    const float* wr = pW + l * 256 + o * 16;
#pragma unroll
    for (int c = 0; c < 16; c++) a += wr[c] * sA[wv][c * 10 + l * 5 + m];
    out[(size_t)n * 160 + i] = a;
  }
  if (w < 32) {
    float a = pb0[w];
    const float* wr = pW0 + w * 32;
#pragma unroll
    for (int c = 0; c < 32; c++) a += wr[c] * sA0[wv][c];
    out[(size_t)N * 160 + (size_t)n * 32 + w] = a;
  }
}

// ---------------------------------------------------------------------------
extern "C" void kernel_launch(void* const* d_in, const int* in_sizes, int n_in,
                              void* d_out, int out_size, void* d_ws, size_t ws_size,
                              hipStream_t stream) {
  const float* x_src  = (const float*)d_in[0];
  const float* x_tar  = (const float*)d_in[1];
  const float* x_src0 = (const float*)d_in[2];
  const float* x_tar0 = (const float*)d_in[3];
  const float* Rw     = (const float*)d_in[4];
  const float* ef     = (const float*)d_in[5];
  const int*   edge   = (const int*)d_in[6];
  const float* r_W1 = (const float*)d_in[10];
  const float* r_b1 = (const float*)d_in[11];
  const float* r_g1 = (const float*)d_in[12];
  const float* r_be1 = (const float*)d_in[13];
  const float* r_W2 = (const float*)d_in[14];
  const float* r_b2 = (const float*)d_in[15];
  const float* r_g2 = (const float*)d_in[16];
  const float* r_be2 = (const float*)d_in[17];
  const float* r_W3 = (const float*)d_in[18];
  const float* r_b3 = (const float*)d_in[19];
  const float* qW  = (const float*)d_in[20];
  const float* qW0 = (const float*)d_in[21];
  const float* qb0 = (const float*)d_in[22];
  const float* kvW  = (const float*)d_in[23];
  const float* kvW0 = (const float*)d_in[24];
  const float* kvb0 = (const float*)d_in[25];
  const float* qng  = (const float*)d_in[26];
  const float* qng0 = (const float*)d_in[27];
  const float* kng  = (const float*)d_in[28];
  const float* kng0 = (const float*)d_in[29];
  const float* pW  = (const float*)d_in[30];
  const float* pW0 = (const float*)d_in[31];
  const float* pb0 = (const float*)d_in[32];

  const int N = in_sizes[0] / 160;   // 10000
  const int E = in_sizes[4] / 50;    // 160000
  float* out = (float*)d_out;

  char* ws = (char*)d_ws;
  size_t off = 0;
  unsigned short* W1T = (unsigned short*)(ws + off); off += 128 * 32 * 2;     // 8KB
  unsigned short* W2T = (unsigned short*)(ws + off); off += 128 * 128 * 2;    // 32KB
  unsigned short* W3T = (unsigned short*)(ws + off); off += 384 * 128 * 2;    // 96KB
  float* logits = (float*)(ws + off); off += (size_t)E * 8 * 4;
  size_t zoff = off;
  unsigned* mxb = (unsigned*)(ws + off); off += (size_t)N * 8 * 4;
  float* den = (float*)(ws + off); off += (size_t)N * 8 * 4;
  size_t zend = off;

  if (ws_size <= off + 128 * 384 * 4) return;
  size_t avail = ws_size - off;
  const size_t vsz = (size_t)E * 160 * 2 + (size_t)E * 32 * 2;
  bool fast = false;
  size_t CE;
  __hip_bfloat16 *vb = nullptr, *v0b = nullptr;
  if (avail >= vsz + (size_t)1024 * 384 * 4) {
    fast = true;
    vb  = (__hip_bfloat16*)(ws + off); off += (size_t)E * 160 * 2;
    v0b = (__hip_bfloat16*)(ws + off); off += (size_t)E * 32 * 2;
    CE = (ws_size - off) / (384 * 4);
  } else {
    CE = avail / (384 * 4);
  }
  if (CE > (size_t)E) CE = E;
  CE &= ~(size_t)127;
  if (CE == 0) return;
  float* w_chunk = (float*)(ws + off);

  hipMemsetAsync(ws + zoff, 0, zend - zoff, stream);
  hipMemsetAsync(d_out, 0, (size_t)out_size * 4, stream);

  prep_kernel<<<(69632 + 255) / 256, 256, 0, stream>>>(r_W1, r_W2, r_W3, W1T, W2T, W3T);

  for (int e0 = 0; e0 < E; e0 += (int)CE) {
    int cnt = E - e0 < (int)CE ? E - e0 : (int)CE;
    radial_mfma<<<(cnt + 127) / 128, 256, 0, stream>>>(
        ef, W1T, W2T, W3T, r_b1, r_g1, r_be1, r_b2, r_g2, r_be2, r_b3, w_chunk, e0, E);
    if (fast)
      edgeA_kernel<1><<<cnt / 4, 256, 0, stream>>>(x_tar, x_tar0, x_src, x_src0, Rw, edge,
                                                   w_chunk, e0, qW, qW0, qb0, kvW, kvW0, kvb0,
                                                   qng, qng0, kng, kng0, vb, v0b, logits, mxb, E);
    else
      edgeA_kernel<0><<<cnt / 4, 256, 0, stream>>>(x_tar, x_tar0, x_src, x_src0, Rw, edge,
                                                   w_chunk, e0, qW, qW0, qb0, kvW, kvW0, kvb0,
                                                   qng, qng0, kng, kng0, vb, v0b, logits, mxb, E);
  }
  edge2_kernel<<<(E * 8 + 255) / 256, 256, 0, stream>>>(edge, logits, mxb, den, E);
  float* att  = out;
  float* att0 = out + (size_t)N * 160;
  if (fast) {
    edgeB_light<<<E / 4, 256, 0, stream>>>(Rw, edge, vb, v0b, logits, mxb, den, att, att0, E);
  } else {
    for (int e0 = 0; e0 < E; e0 += (int)CE) {
      int cnt = E - e0 < (int)CE ? E - e0 : (int)CE;
      radial_mfma<<<(cnt + 127) / 128, 256, 0, stream>>>(
          ef, W1T, W2T, W3T, r_b1, r_g1, r_be1, r_b2, r_g2, r_be2, r_b3, w_chunk, e0, E);
      edgeB_rec<<<cnt / 4, 256, 0, stream>>>(x_src, x_src0, Rw, edge, w_chunk, e0,
                                             kvW, kvW0, kvb0, logits, mxb, den, att, att0, E);
    }
  }
  node_kernel<<<(N + 3) / 4, 256, 0, stream>>>(pW, pW0, pb0, out, N);
}

// Round 4
// 651.144 us; speedup vs baseline: 2.5192x; 1.5857x over previous
//
#include <hip/hip_runtime.h>
#include <hip/hip_bf16.h>
#include <math.h>

// N=10000, E=160000, C=16, C0=32, L=2, M=5, H=8, R_IN=32, R_HID=128, REQ=384

typedef short bf16x8 __attribute__((ext_vector_type(8)));
typedef float f32x4 __attribute__((ext_vector_type(4)));

__device__ __forceinline__ float waveSum(float v) {
#pragma unroll
  for (int m = 1; m < 64; m <<= 1) v += __shfl_xor(v, m, 64);
  return v;
}
__device__ __forceinline__ unsigned encf(float f) {
  unsigned u = __float_as_uint(f);
  return (u & 0x80000000u) ? ~u : (u | 0x80000000u);
}
__device__ __forceinline__ float decf(unsigned u) {
  return (u & 0x80000000u) ? __uint_as_float(u & 0x7FFFFFFFu) : __uint_as_float(~u);
}
__device__ __forceinline__ unsigned short f2bu(float f) {
  __hip_bfloat16 h = __float2bfloat16(f);
  unsigned short u;
  __builtin_memcpy(&u, &h, 2);
  return u;
}

// ---------------------------------------------------------------------------
// Prep: transpose radial weights to bf16 [n][k] layout
// ---------------------------------------------------------------------------
__global__ __launch_bounds__(256) void prep_kernel(
    const float* __restrict__ W1, const float* __restrict__ W2,
    const float* __restrict__ W3,
    unsigned short* __restrict__ W1T, unsigned short* __restrict__ W2T,
    unsigned short* __restrict__ W3T) {
  int idx = blockIdx.x * 256 + threadIdx.x;
  if (idx < 128 * 32) {
    int n = idx >> 5, k = idx & 31;
    W1T[idx] = f2bu(W1[k * 128 + n]);
  }
  int i2 = idx - 128 * 32;
  if (i2 >= 0 && i2 < 128 * 128) {
    int n = i2 >> 7, k = i2 & 127;
    W2T[i2] = f2bu(W2[k * 128 + n]);
  }
  int i3 = idx - 128 * 32 - 128 * 128;
  if (i3 >= 0 && i3 < 384 * 128) {
    int n = i3 >> 7, k = i3 & 127;
    W3T[i3] = f2bu(W3[k * 384 + n]);
  }
}

// ---------------------------------------------------------------------------
// Node prep: hoist channel-mix GEMMs from edges to nodes (mix commutes with
// rotation).  Per node: qmixN[160], q0N[32] (fully LN'd), kvmixN[320],
// kv0N[64] (no LN).  1 wave/node, 4 nodes/block.
// ---------------------------------------------------------------------------
__global__ __launch_bounds__(256) void nodeprep_kernel(
    const float* __restrict__ xt, const float* __restrict__ xt0,
    const float* __restrict__ xs, const float* __restrict__ xs0,
    const float* __restrict__ qW, const float* __restrict__ qW0,
    const float* __restrict__ qb0, const float* __restrict__ qng0,
    const float* __restrict__ kvW, const float* __restrict__ kvW0,
    const float* __restrict__ kvb0,
    float* __restrict__ qmixN, float* __restrict__ q0N,
    float* __restrict__ kvmixN, float* __restrict__ kv0N, int N) {
  __shared__ float sXT[4][160];
  __shared__ float sXS[4][160];
  __shared__ float sX0T[4][32];
  __shared__ float sX0S[4][32];
  const int tid = threadIdx.x, wv = tid >> 6, w = tid & 63;
  const int n = blockIdx.x * 4 + wv;
  if (n < N) {
    for (int i = w; i < 160; i += 64) {
      sXT[wv][i] = xt[(size_t)n * 160 + i];
      sXS[wv][i] = xs[(size_t)n * 160 + i];
    }
    if (w < 32) { sX0T[wv][w] = xt0[n * 32 + w]; sX0S[wv][w] = xs0[n * 32 + w]; }
  }
  __syncthreads();
  if (n >= N) return;
  // q mix: qmix[o,lm] = sum_c qW[l,o,c] * x[c,lm]
  for (int i = w; i < 160; i += 64) {
    int o = i / 10, lm = i % 10, l = lm / 5;
    const float4* wr = (const float4*)(qW + l * 256 + o * 16);
    float a = 0.f;
#pragma unroll
    for (int c4 = 0; c4 < 4; c4++) {
      float4 ww = wr[c4];
      a += ww.x * sXT[wv][(c4 * 4 + 0) * 10 + lm] + ww.y * sXT[wv][(c4 * 4 + 1) * 10 + lm]
         + ww.z * sXT[wv][(c4 * 4 + 2) * 10 + lm] + ww.w * sXT[wv][(c4 * 4 + 3) * 10 + lm];
    }
    qmixN[(size_t)n * 160 + i] = a;
  }
  // kv mix (32 out channels)
  for (int i = w; i < 320; i += 64) {
    int o = i / 10, lm = i % 10, l = lm / 5;
    const float4* wr = (const float4*)(kvW + l * 512 + o * 16);
    float a = 0.f;
#pragma unroll
    for (int c4 = 0; c4 < 4; c4++) {
      float4 ww = wr[c4];
      a += ww.x * sXS[wv][(c4 * 4 + 0) * 10 + lm] + ww.y * sXS[wv][(c4 * 4 + 1) * 10 + lm]
         + ww.z * sXS[wv][(c4 * 4 + 2) * 10 + lm] + ww.w * sXS[wv][(c4 * 4 + 3) * 10 + lm];
    }
    kvmixN[(size_t)n * 320 + i] = a;
  }
  // q0: GEMM + LN * qng0 (fully hoisted)
  {
    float a = 0.f;
    if (w < 32) {
      a = qb0[w];
      const float4* wr = (const float4*)(qW0 + w * 32);
#pragma unroll
      for (int c4 = 0; c4 < 8; c4++) {
        float4 ww = wr[c4];
        a += ww.x * sX0T[wv][c4 * 4] + ww.y * sX0T[wv][c4 * 4 + 1]
           + ww.z * sX0T[wv][c4 * 4 + 2] + ww.w * sX0T[wv][c4 * 4 + 3];
      }
    }
    float vv = (w < 32) ? a : 0.f;
    float s1 = waveSum(vv), s2 = waveSum(vv * vv);
    float mu = s1 / 32.f, var = s2 / 32.f - mu * mu;
    if (w < 32) q0N[(size_t)n * 32 + w] = (a - mu) * rsqrtf(var + 1e-5f) * qng0[w];
  }
  // kv0 (64 outs, no LN here)
  {
    float a = kvb0[w];
    const float4* wr = (const float4*)(kvW0 + w * 32);
#pragma unroll
    for (int c4 = 0; c4 < 8; c4++) {
      float4 ww = wr[c4];
      a += ww.x * sX0S[wv][c4 * 4] + ww.y * sX0S[wv][c4 * 4 + 1]
         + ww.z * sX0S[wv][c4 * 4 + 2] + ww.w * sX0S[wv][c4 * 4 + 3];
    }
    kv0N[(size_t)n * 64 + w] = a;
  }
}

// ---------------------------------------------------------------------------
// Kernel 1: MFMA radial MLP (unchanged from round 3)
// ---------------------------------------------------------------------------
__global__ __launch_bounds__(256) void radial_mfma(
    const float* __restrict__ ef,
    const unsigned short* __restrict__ W1T, const unsigned short* __restrict__ W2T,
    const unsigned short* __restrict__ W3T,
    const float* __restrict__ b1, const float* __restrict__ g1, const float* __restrict__ be1,
    const float* __restrict__ b2, const float* __restrict__ g2, const float* __restrict__ be2,
    const float* __restrict__ b3,
    float* __restrict__ w_chunk, int e0, int E) {
  __shared__ unsigned short sA[128 * 128];
  __shared__ unsigned short sW[128 * 128];
  const int tid = threadIdx.x;
  const int lane = tid & 63, wid = tid >> 6;
  const int eb = blockIdx.x * 128;
  const int colq = lane & 15, rowq = lane >> 4;

  float b1v[8], g1v[8], be1v[8], b2v[8], g2v[8], be2v[8];
#pragma unroll
  for (int nt = 0; nt < 8; nt++) {
    int c = nt * 16 + colq;
    b1v[nt] = b1[c]; g1v[nt] = g1[c]; be1v[nt] = be1[c];
    b2v[nt] = b2[c]; g2v[nt] = g2[c]; be2v[nt] = be2[c];
  }

  for (int idx = tid; idx < 1024; idx += 256) {
    int e = idx >> 3, k4 = idx & 7;
    int ee = e0 + eb + e; if (ee >= E) ee = E - 1;
    float4 v = *(const float4*)&ef[(size_t)ee * 32 + k4 * 4];
    ushort4 uu = make_ushort4(f2bu(v.x), f2bu(v.y), f2bu(v.z), f2bu(v.w));
    unsigned bo = (unsigned)e * 256 + (((unsigned)k4 * 8) ^ ((e & 7) << 4));
    *(ushort4*)((char*)sA + bo) = uu;
  }
  for (int idx = tid; idx < 512; idx += 256) {
    int n = idx >> 2, j = idx & 3;
    uint4 v = *(const uint4*)&W1T[n * 32 + j * 8];
    unsigned bo = (unsigned)n * 256 + (((unsigned)j * 16) ^ ((n & 7) << 4));
    *(uint4*)((char*)sW + bo) = v;
  }
  __syncthreads();

  f32x4 zz = {0.f, 0.f, 0.f, 0.f};
  f32x4 acc[2][8];
#pragma unroll
  for (int mt = 0; mt < 2; mt++)
#pragma unroll
    for (int nt = 0; nt < 8; nt++) acc[mt][nt] = zz;

  {
    bf16x8 af[2];
#pragma unroll
    for (int mt = 0; mt < 2; mt++) {
      int row = wid * 32 + mt * 16 + colq;
      unsigned bo = (unsigned)row * 256 + (((unsigned)rowq * 16) ^ ((row & 7) << 4));
      af[mt] = *(const bf16x8*)((const char*)sA + bo);
    }
#pragma unroll
    for (int nt = 0; nt < 8; nt++) {
      int n = nt * 16 + colq;
      unsigned bo = (unsigned)n * 256 + (((unsigned)rowq * 16) ^ ((n & 7) << 4));
      bf16x8 bfv = *(const bf16x8*)((const char*)sW + bo);
#pragma unroll
      for (int mt = 0; mt < 2; mt++)
        acc[mt][nt] = __builtin_amdgcn_mfma_f32_16x16x32_bf16(af[mt], bfv, acc[mt][nt], 0, 0, 0);
    }
  }
  __syncthreads();

#pragma unroll
  for (int mt = 0; mt < 2; mt++) {
#pragma unroll
    for (int r = 0; r < 4; r++) {
      float s1 = 0.f, s2 = 0.f;
#pragma unroll
      for (int nt = 0; nt < 8; nt++) {
        float v = acc[mt][nt][r] + b1v[nt];
        s1 += v; s2 += v * v;
      }
#pragma unroll
      for (int off = 1; off < 16; off <<= 1) { s1 += __shfl_xor(s1, off, 64); s2 += __shfl_xor(s2, off, 64); }
      float mu = s1 * (1.f / 128.f);
      float rs = rsqrtf(s2 * (1.f / 128.f) - mu * mu + 1e-5f);
      int row = wid * 32 + mt * 16 + rowq * 4 + r;
      unsigned rbase = (unsigned)row * 256;
      unsigned swz = (row & 7) << 4;
#pragma unroll
      for (int nt = 0; nt < 8; nt++) {
        float v = (acc[mt][nt][r] + b1v[nt] - mu) * rs * g1v[nt] + be1v[nt];
        v = v / (1.f + __expf(-v));
        *(unsigned short*)((char*)sA + rbase + ((((unsigned)(nt * 16 + colq)) * 2) ^ swz)) = f2bu(v);
      }
    }
  }
  for (int idx = tid; idx < 2048; idx += 256) {
    int n = idx >> 4, j = idx & 15;
    uint4 v = *(const uint4*)&W2T[n * 128 + j * 8];
    unsigned bo = (unsigned)n * 256 + (((unsigned)j * 16) ^ ((n & 7) << 4));
    *(uint4*)((char*)sW + bo) = v;
  }
  __syncthreads();

#pragma unroll
  for (int mt = 0; mt < 2; mt++)
#pragma unroll
    for (int nt = 0; nt < 8; nt++) acc[mt][nt] = zz;
#pragma unroll
  for (int ks = 0; ks < 4; ks++) {
    bf16x8 af[2];
#pragma unroll
    for (int mt = 0; mt < 2; mt++) {
      int row = wid * 32 + mt * 16 + colq;
      unsigned bo = (unsigned)row * 256 + (((unsigned)(ks * 64 + rowq * 16)) ^ ((row & 7) << 4));
      af[mt] = *(const bf16x8*)((const char*)sA + bo);
    }
#pragma unroll
    for (int nt = 0; nt < 8; nt++) {
      int n = nt * 16 + colq;
      unsigned bo = (unsigned)n * 256 + (((unsigned)(ks * 64 + rowq * 16)) ^ ((n & 7) << 4));
      bf16x8 bfv = *(const bf16x8*)((const char*)sW + bo);
#pragma unroll
      for (int mt = 0; mt < 2; mt++)
        acc[mt][nt] = __builtin_amdgcn_mfma_f32_16x16x32_bf16(af[mt], bfv, acc[mt][nt], 0, 0, 0);
    }
  }
  __syncthreads();

#pragma unroll
  for (int mt = 0; mt < 2; mt++) {
#pragma unroll
    for (int r = 0; r < 4; r++) {
      float s1 = 0.f, s2 = 0.f;
#pragma unroll
      for (int nt = 0; nt < 8; nt++) {
        float v = acc[mt][nt][r] + b2v[nt];
        s1 += v; s2 += v * v;
      }
#pragma unroll
      for (int off = 1; off < 16; off <<= 1) { s1 += __shfl_xor(s1, off, 64); s2 += __shfl_xor(s2, off, 64); }
      float mu = s1 * (1.f / 128.f);
      float rs = rsqrtf(s2 * (1.f / 128.f) - mu * mu + 1e-5f);
      int row = wid * 32 + mt * 16 + rowq * 4 + r;
      unsigned rbase = (unsigned)row * 256;
      unsigned swz = (row & 7) << 4;
#pragma unroll
      for (int nt = 0; nt < 8; nt++) {
        float v = (acc[mt][nt][r] + b2v[nt] - mu) * rs * g2v[nt] + be2v[nt];
        v = v / (1.f + __expf(-v));
        *(unsigned short*)((char*)sA + rbase + ((((unsigned)(nt * 16 + colq)) * 2) ^ swz)) = f2bu(v);
      }
    }
  }

  for (int cc = 0; cc < 3; cc++) {
    if (cc > 0) __syncthreads();
    for (int idx = tid; idx < 2048; idx += 256) {
      int n = idx >> 4, j = idx & 15;
      uint4 v = *(const uint4*)&W3T[(size_t)(cc * 128 + n) * 128 + j * 8];
      unsigned bo = (unsigned)n * 256 + (((unsigned)j * 16) ^ ((n & 7) << 4));
      *(uint4*)((char*)sW + bo) = v;
    }
    __syncthreads();
    f32x4 a3[2][8];
#pragma unroll
    for (int mt = 0; mt < 2; mt++)
#pragma unroll
      for (int nt = 0; nt < 8; nt++) a3[mt][nt] = zz;
#pragma unroll
    for (int ks = 0; ks < 4; ks++) {
      bf16x8 af[2];
#pragma unroll
      for (int mt = 0; mt < 2; mt++) {
        int row = wid * 32 + mt * 16 + colq;
        unsigned bo = (unsigned)row * 256 + (((unsigned)(ks * 64 + rowq * 16)) ^ ((row & 7) << 4));
        af[mt] = *(const bf16x8*)((const char*)sA + bo);
      }
#pragma unroll
      for (int nt = 0; nt < 8; nt++) {
        int n = nt * 16 + colq;
        unsigned bo = (unsigned)n * 256 + (((unsigned)(ks * 64 + rowq * 16)) ^ ((n & 7) << 4));
        bf16x8 bfv = *(const bf16x8*)((const char*)sW + bo);
#pragma unroll
        for (int mt = 0; mt < 2; mt++)
          a3[mt][nt] = __builtin_amdgcn_mfma_f32_16x16x32_bf16(af[mt], bfv, a3[mt][nt], 0, 0, 0);
      }
    }
#pragma unroll
    for (int nt = 0; nt < 8; nt++) {
      int col = cc * 128 + nt * 16 + colq;
      float b3v = b3[col];
#pragma unroll
      for (int mt = 0; mt < 2; mt++) {
#pragma unroll
        for (int r = 0; r < 4; r++) {
          int row_e = eb + wid * 32 + mt * 16 + rowq * 4 + r;
          w_chunk[(size_t)row_e * 384 + col] = a3[mt][nt][r] + b3v;
        }
      }
    }
  }
}

// ---------------------------------------------------------------------------
// Kernel 2: per-edge rotate + conv + norms + logits.  1 wave/edge, 4/block.
// All mixes pre-hoisted to nodes; only per-edge data touched here.
// ---------------------------------------------------------------------------
template <int STOREV>
__global__ __launch_bounds__(256) void edgeA_kernel(
    const float* __restrict__ qmixN, const float* __restrict__ q0N,
    const float* __restrict__ kvmixN, const float* __restrict__ kv0N,
    const float* __restrict__ Rw, const int* __restrict__ edge,
    const float* __restrict__ w_chunk, int e0,
    const float* __restrict__ qng, const float* __restrict__ kng,
    const float* __restrict__ kng0,
    __hip_bfloat16* __restrict__ v_buf, __hip_bfloat16* __restrict__ v0_buf,
    float* __restrict__ logits, unsigned* __restrict__ mx, int E) {
  __shared__ float sR[4][52];
  __shared__ float sMQ[4][160];
  __shared__ float sQ[4][160];
  __shared__ float sMK[4][320];
  __shared__ float sKV[4][320];
  __shared__ float sW[4][384];
  __shared__ float sY[4][320];
  __shared__ float sQ0[4][32];
  __shared__ float sK0[4][64];
  __shared__ float sY0[4][64];
  const int tid = threadIdx.x, wv = tid >> 6, w = tid & 63;
  const int e = e0 + blockIdx.x * 4 + wv;
  const int src = edge[e], dst = edge[E + e];

  if (w < 50) sR[wv][w] = Rw[(size_t)e * 50 + w];
  for (int i = w; i < 160; i += 64) sMQ[wv][i] = qmixN[(size_t)dst * 160 + i];
  for (int i = w; i < 320; i += 64) sMK[wv][i] = kvmixN[(size_t)src * 320 + i];
  {
    const float4* wc = (const float4*)w_chunk + (size_t)(e - e0) * 96;
    for (int j = w; j < 96; j += 64) *(float4*)&sW[wv][j * 4] = wc[j];
  }
  if (w < 32) sQ0[wv][w] = q0N[(size_t)dst * 32 + w];
  sK0[wv][w] = kv0N[(size_t)src * 64 + w];
  __syncthreads();

  // rotate q (per-lane elements i=w, w+64, w+128) + rms + scale
  {
    float rq[3]; float p = 0.f;
#pragma unroll
    for (int r = 0; r < 3; r++) {
      int i = w + r * 64;
      rq[r] = 0.f;
      if (i < 160) {
        int lm = i % 10, l = lm / 5, m = lm % 5;
        const float* rr = &sR[wv][l * 25 + m * 5];
        const float* xx = &sMK[wv][0];  // placeholder to keep symmetry (unused)
        (void)xx;
        const float* qq = &sMQ[wv][(i - lm) + l * 5];
        rq[r] = rr[0] * qq[0] + rr[1] * qq[1] + rr[2] * qq[2] + rr[3] * qq[3] + rr[4] * qq[4];
        p += rq[r] * rq[r];
      }
    }
    float rms = rsqrtf(waveSum(p) * (1.f / 160.f) + 1e-5f);
#pragma unroll
    for (int r = 0; r < 3; r++) {
      int i = w + r * 64;
      if (i < 160) sQ[wv][i] = rq[r] * rms * qng[i / 10];
    }
  }
  // rotate kv
  for (int i = w; i < 320; i += 64) {
    int lm = i % 10, l = lm / 5, m = lm % 5;
    const float* rr = &sR[wv][l * 25 + m * 5];
    const float* xx = &sMK[wv][(i - lm) + l * 5];
    sKV[wv][i] = rr[0] * xx[0] + rr[1] * xx[1] + rr[2] * xx[2] + rr[3] * xx[3] + rr[4] * xx[4];
  }
  __syncthreads();

  // SO(2) conv with per-edge radial weights
  {
    const float* wa = sW[wv];
    for (int i = w; i < 320; i += 64) {
      int o = i / 10, lm = i % 10, l = lm / 5, m = lm % 5;
      int base = o * 8 + l * 4;
      int xb = i - m;
      float yv;
      if (m < 2) {
        int j = 1 - m;
        yv = wa[base + 2 + j] * sKV[wv][xb + 3 + j] + wa[base + j] * sKV[wv][xb + 1 - j];
      } else if (m == 2) {
        yv = wa[320 + o * 2 + l] * sKV[wv][xb + 2];
      } else {
        int j = m - 3;
        yv = wa[base + j] * sKV[wv][xb + 3 + j] - wa[base + 2 + j] * sKV[wv][xb + 1 - j];
      }
      sY[wv][i] = yv;
    }
    sY0[wv][w] = wa[256 + w] * sK0[wv][w];
  }
  // k eq_norm (same-lane elements) + k0 LN
  {
    float kv_[3]; float p = 0.f;
#pragma unroll
    for (int r = 0; r < 3; r++) {
      int i = w + r * 64;
      kv_[r] = (i < 160) ? sY[wv][i] : 0.f;
      p += kv_[r] * kv_[r];
    }
    float rms = rsqrtf(waveSum(p) * (1.f / 160.f) + 1e-5f);
#pragma unroll
    for (int r = 0; r < 3; r++) {
      int i = w + r * 64;
      if (i < 160) sY[wv][i] = kv_[r] * rms * kng[i / 10];
    }
    float vv = (w < 32) ? sY0[wv][w] : 0.f;
    float s1 = waveSum(vv), s2 = waveSum(vv * vv);
    float mu = s1 / 32.f, var = s2 / 32.f - mu * mu;
    float rs0 = rsqrtf(var + 1e-5f);
    if (w < 32) sY0[wv][w] = (vv - mu) * rs0 * kng0[w];
  }
  // q.k products (same-lane)
#pragma unroll
  for (int r = 0; r < 3; r++) {
    int i = w + r * 64;
    if (i < 160) sMQ[wv][i] = sQ[wv][i] * sY[wv][i];
  }
  __syncthreads();

  if (w < 8) {
    float s = 0.f;
#pragma unroll
    for (int i = 0; i < 20; i++) s += sMQ[wv][w * 20 + i];
#pragma unroll
    for (int j = 0; j < 4; j++) s += sQ0[wv][w * 4 + j] * sY0[wv][w * 4 + j];
    float lg = s * 0.70710678118654752f;
    logits[(size_t)e * 8 + w] = lg;
    atomicMax(&mx[dst * 8 + w], encf(lg));
  }
  if (STOREV) {
    for (int i = w; i < 160; i += 64)
      v_buf[(size_t)e * 160 + i] = __float2bfloat16(sY[wv][160 + i]);
    if (w < 32) v0_buf[(size_t)e * 32 + w] = __float2bfloat16(sY0[wv][32 + w]);
  }
}

// ---------------------------------------------------------------------------
// Kernel 3: denominator
// ---------------------------------------------------------------------------
__global__ __launch_bounds__(256) void edge2_kernel(
    const int* __restrict__ edge, const float* __restrict__ logits,
    const unsigned* __restrict__ mx, float* __restrict__ den, int E) {
  int idx = blockIdx.x * 256 + threadIdx.x;
  if (idx >= E * 8) return;
  int e = idx >> 3, h = idx & 7;
  int dst = edge[E + e];
  float m = decf(mx[dst * 8 + h]);
  atomicAdd(&den[dst * 8 + h], __expf(logits[idx] - m));
}

// ---------------------------------------------------------------------------
// Kernel 4a (fast): alpha * v (bf16), inverse rotation, scatter-add
// ---------------------------------------------------------------------------
__global__ __launch_bounds__(256) void edgeB_light(
    const float* __restrict__ Rw, const int* __restrict__ edge,
    const __hip_bfloat16* __restrict__ v_buf, const __hip_bfloat16* __restrict__ v0_buf,
    const float* __restrict__ logits, const unsigned* __restrict__ mx,
    const float* __restrict__ den,
    float* __restrict__ att, float* __restrict__ att0, int E) {
  __shared__ float sR[4][52];
  __shared__ float sV[4][160];
  __shared__ float sAl[4][8];
  const int tid = threadIdx.x;
  const int wv = tid >> 6, w = tid & 63;
  const int e = blockIdx.x * 4 + wv;
  const int dst = edge[E + e];
  if (w < 8) {
    float m = decf(mx[dst * 8 + w]);
    sAl[wv][w] = __expf(logits[(size_t)e * 8 + w] - m) / den[dst * 8 + w];
  }
  if (w < 50) sR[wv][w] = Rw[(size_t)e * 50 + w];
  for (int i = w; i < 160; i += 64) sV[wv][i] = __bfloat162float(v_buf[(size_t)e * 160 + i]);
  __syncthreads();
  for (int i = w; i < 160; i += 64) {
    int c = i / 10, lm = i % 10, l = lm / 5, m = lm % 5;
    float a = 0.f;
#pragma unroll
    for (int n = 0; n < 5; n++) a += sR[wv][l * 25 + n * 5 + m] * sV[wv][c * 10 + l * 5 + n];
    atomicAdd(&att[(size_t)dst * 160 + i], sAl[wv][c >> 1] * a);
  }
  if (w < 32)
    atomicAdd(&att0[(size_t)dst * 32 + w], sAl[wv][w >> 2] * __bfloat162float(v0_buf[(size_t)e * 32 + w]));
}

// ---------------------------------------------------------------------------
// Kernel 4b (fallback): recompute v branch from kvmixN + w_chunk
// ---------------------------------------------------------------------------
__global__ __launch_bounds__(256) void edgeB_rec(
    const float* __restrict__ kvmixN, const float* __restrict__ kv0N,
    const float* __restrict__ Rw, const int* __restrict__ edge,
    const float* __restrict__ w_chunk, int e0,
    const float* __restrict__ logits, const unsigned* __restrict__ mx,
    const float* __restrict__ den,
    float* __restrict__ att, float* __restrict__ att0, int E) {
  __shared__ float sR[4][52];
  __shared__ float sM[4][160];
  __shared__ float sT[4][160];
  __shared__ float sV[4][160];
  __shared__ float sW[4][384];
  __shared__ float sAl[4][8];
  const int tid = threadIdx.x;
  const int wv = tid >> 6, w = tid & 63;
  const int e = e0 + blockIdx.x * 4 + wv;
  const int src = edge[e], dst = edge[E + e];
  if (w < 50) sR[wv][w] = Rw[(size_t)e * 50 + w];
  for (int i = w; i < 160; i += 64) sM[wv][i] = kvmixN[(size_t)src * 320 + 160 + i];
  {
    const float4* wc = (const float4*)w_chunk + (size_t)(e - e0) * 96;
    for (int j = w; j < 96; j += 64) *(float4*)&sW[wv][j * 4] = wc[j];
  }
  if (w < 8) {
    float m = decf(mx[dst * 8 + w]);
    sAl[wv][w] = __expf(logits[(size_t)e * 8 + w] - m) / den[dst * 8 + w];
  }
  __syncthreads();
  // rotate v-mix
  for (int i = w; i < 160; i += 64) {
    int lm = i % 10, l = lm / 5, m = lm % 5;
    const float* rr = &sR[wv][l * 25 + m * 5];
    const float* xx = &sM[wv][(i - lm) + l * 5];
    sT[wv][i] = rr[0] * xx[0] + rr[1] * xx[1] + rr[2] * xx[2] + rr[3] * xx[3] + rr[4] * xx[4];
  }
  __syncthreads();
  // conv (v channels o=16..31)
  float v0 = 0.f;
  {
    const float* wa = sW[wv];
    for (int i = w; i < 160; i += 64) {
      int o2 = i / 10, lm = i % 10, l = lm / 5, m = lm % 5;
      int o = 16 + o2;
      int base = o * 8 + l * 4;
      int xb = i - m;
      float yv;
      if (m < 2) {
        int j = 1 - m;
        yv = wa[base + 2 + j] * sT[wv][xb + 3 + j] + wa[base + j] * sT[wv][xb + 1 - j];
      } else if (m == 2) {
        yv = wa[320 + o * 2 + l] * sT[wv][xb + 2];
      } else {
        int j = m - 3;
        yv = wa[base + j] * sT[wv][xb + 3 + j] - wa[base + 2 + j] * sT[wv][xb + 1 - j];
      }
      sV[wv][i] = yv;
    }
    if (w < 32) v0 = wa[288 + w] * kv0N[(size_t)src * 64 + 32 + w];
  }
  __syncthreads();
  for (int i = w; i < 160; i += 64) {
    int c = i / 10, lm = i % 10, l = lm / 5, m = lm % 5;
    float a = 0.f;
#pragma unroll
    for (int n = 0; n < 5; n++) a += sR[wv][l * 25 + n * 5 + m] * sV[wv][c * 10 + l * 5 + n];
    atomicAdd(&att[(size_t)dst * 160 + i], sAl[wv][c >> 1] * a);
  }
  if (w < 32) atomicAdd(&att0[(size_t)dst * 32 + w], sAl[wv][w >> 2] * v0);
}

// ---------------------------------------------------------------------------
// Kernel 5: per-node output projection, in place over d_out
// ---------------------------------------------------------------------------
__global__ __launch_bounds__(256) void node_kernel(
    const float* __restrict__ pW, const float* __restrict__ pW0,
    const float* __restrict__ pb0, float* __restrict__ out, int N) {
  __shared__ float sA[4][160];
  __shared__ float sA0[4][32];
  const int tid = threadIdx.x;
  const int wv = tid >> 6, w = tid & 63;
  const int n = blockIdx.x * 4 + wv;
  if (n < N) {
    for (int i = w; i < 160; i += 64) sA[wv][i] = out[(size_t)n * 160 + i];
    if (w < 32) sA0[wv][w] = out[(size_t)N * 160 + (size_t)n * 32 + w];
  }
  __syncthreads();
  if (n >= N) return;
  for (int i = w; i < 160; i += 64) {
    int o = i / 10, lm = i % 10, l = lm / 5, m = lm % 5;
    float a = 0.f;
    const float* wr = pW + l * 256 + o * 16;
#pragma unroll
    for (int c = 0; c < 16; c++) a += wr[c] * sA[wv][c * 10 + l * 5 + m];
    out[(size_t)n * 160 + i] = a;
  }
  if (w < 32) {
    float a = pb0[w];
    const float* wr = pW0 + w * 32;
#pragma unroll
    for (int c = 0; c < 32; c++) a += wr[c] * sA0[wv][c];
    out[(size_t)N * 160 + (size_t)n * 32 + w] = a;
  }
}

// ---------------------------------------------------------------------------
extern "C" void kernel_launch(void* const* d_in, const int* in_sizes, int n_in,
                              void* d_out, int out_size, void* d_ws, size_t ws_size,
                              hipStream_t stream) {
  const float* x_src  = (const float*)d_in[0];
  const float* x_tar  = (const float*)d_in[1];
  const float* x_src0 = (const float*)d_in[2];
  const float* x_tar0 = (const float*)d_in[3];
  const float* Rw     = (const float*)d_in[4];
  const float* ef     = (const float*)d_in[5];
  const int*   edge   = (const int*)d_in[6];
  const float* r_W1 = (const float*)d_in[10];
  const float* r_b1 = (const float*)d_in[11];
  const float* r_g1 = (const float*)d_in[12];
  const float* r_be1 = (const float*)d_in[13];
  const float* r_W2 = (const float*)d_in[14];
  const float* r_b2 = (const float*)d_in[15];
  const float* r_g2 = (const float*)d_in[16];
  const float* r_be2 = (const float*)d_in[17];
  const float* r_W3 = (const float*)d_in[18];
  const float* r_b3 = (const float*)d_in[19];
  const float* qW  = (const float*)d_in[20];
  const float* qW0 = (const float*)d_in[21];
  const float* qb0 = (const float*)d_in[22];
  const float* kvW  = (const float*)d_in[23];
  const float* kvW0 = (const float*)d_in[24];
  const float* kvb0 = (const float*)d_in[25];
  const float* qng  = (const float*)d_in[26];
  const float* qng0 = (const float*)d_in[27];
  const float* kng  = (const float*)d_in[28];
  const float* kng0 = (const float*)d_in[29];
  const float* pW  = (const float*)d_in[30];
  const float* pW0 = (const float*)d_in[31];
  const float* pb0 = (const float*)d_in[32];

  const int N = in_sizes[0] / 160;   // 10000
  const int E = in_sizes[4] / 50;    // 160000
  float* out = (float*)d_out;

  char* ws = (char*)d_ws;
  size_t off = 0;
  unsigned short* W1T = (unsigned short*)(ws + off); off += 128 * 32 * 2;
  unsigned short* W2T = (unsigned short*)(ws + off); off += 128 * 128 * 2;
  unsigned short* W3T = (unsigned short*)(ws + off); off += 384 * 128 * 2;
  float* logits = (float*)(ws + off); off += (size_t)E * 8 * 4;
  size_t zoff = off;
  unsigned* mxb = (unsigned*)(ws + off); off += (size_t)N * 8 * 4;
  float* den = (float*)(ws + off); off += (size_t)N * 8 * 4;
  size_t zend = off;
  float* qmixN  = (float*)(ws + off); off += (size_t)N * 160 * 4;
  float* q0N    = (float*)(ws + off); off += (size_t)N * 32 * 4;
  float* kvmixN = (float*)(ws + off); off += (size_t)N * 320 * 4;
  float* kv0N   = (float*)(ws + off); off += (size_t)N * 64 * 4;

  if (ws_size <= off + 128 * 384 * 4) return;
  size_t avail = ws_size - off;
  const size_t vsz = (size_t)E * 160 * 2 + (size_t)E * 32 * 2;
  bool fast = false;
  size_t CE;
  __hip_bfloat16 *vb = nullptr, *v0b = nullptr;
  if (avail >= vsz + (size_t)1024 * 384 * 4) {
    fast = true;
    vb  = (__hip_bfloat16*)(ws + off); off += (size_t)E * 160 * 2;
    v0b = (__hip_bfloat16*)(ws + off); off += (size_t)E * 32 * 2;
    CE = (ws_size - off) / (384 * 4);
  } else {
    CE = avail / (384 * 4);
  }
  if (CE > (size_t)E) CE = E;
  CE &= ~(size_t)127;
  if (CE == 0) return;
  float* w_chunk = (float*)(ws + off);

  hipMemsetAsync(ws + zoff, 0, zend - zoff, stream);
  hipMemsetAsync(d_out, 0, (size_t)out_size * 4, stream);

  prep_kernel<<<(69632 + 255) / 256, 256, 0, stream>>>(r_W1, r_W2, r_W3, W1T, W2T, W3T);
  nodeprep_kernel<<<(N + 3) / 4, 256, 0, stream>>>(
      x_tar, x_tar0, x_src, x_src0, qW, qW0, qb0, qng0, kvW, kvW0, kvb0,
      qmixN, q0N, kvmixN, kv0N, N);

  for (int e0 = 0; e0 < E; e0 += (int)CE) {
    int cnt = E - e0 < (int)CE ? E - e0 : (int)CE;
    radial_mfma<<<(cnt + 127) / 128, 256, 0, stream>>>(
        ef, W1T, W2T, W3T, r_b1, r_g1, r_be1, r_b2, r_g2, r_be2, r_b3, w_chunk, e0, E);
    if (fast)
      edgeA_kernel<1><<<cnt / 4, 256, 0, stream>>>(qmixN, q0N, kvmixN, kv0N, Rw, edge,
                                                   w_chunk, e0, qng, kng, kng0,
                                                   vb, v0b, logits, mxb, E);
    else
      edgeA_kernel<0><<<cnt / 4, 256, 0, stream>>>(qmixN, q0N, kvmixN, kv0N, Rw, edge,
                                                   w_chunk, e0, qng, kng, kng0,
                                                   vb, v0b, logits, mxb, E);
  }
  edge2_kernel<<<(E * 8 + 255) / 256, 256, 0, stream>>>(edge, logits, mxb, den, E);
  float* att  = out;
  float* att0 = out + (size_t)N * 160;
  if (fast) {
    edgeB_light<<<E / 4, 256, 0, stream>>>(Rw, edge, vb, v0b, logits, mxb, den, att, att0, E);
  } else {
    for (int e0 = 0; e0 < E; e0 += (int)CE) {
      int cnt = E - e0 < (int)CE ? E - e0 : (int)CE;
      radial_mfma<<<(cnt + 127) / 128, 256, 0, stream>>>(
          ef, W1T, W2T, W3T, r_b1, r_g1, r_be1, r_b2, r_g2, r_be2, r_b3, w_chunk, e0, E);
      edgeB_rec<<<cnt / 4, 256, 0, stream>>>(kvmixN, kv0N, Rw, edge, w_chunk, e0,
                                             logits, mxb, den, att, att0, E);
    }
  }
  node_kernel<<<(N + 3) / 4, 256, 0, stream>>>(pW, pW0, pb0, out, N);
}